// Round 1
// baseline (587.724 us; speedup 1.0000x reference)
//
#include <hip/hip_runtime.h>

#define IN_F 4096
#define OUT_F 4096
#define RANK 16
#define NTOK 8192
#define KP 4128            // IN_F + 16 (lora cols) + 16 (zero pad) -> multiple of 32
#define NKSTEP (KP / 32)   // 129

typedef __bf16 bf16x8 __attribute__((ext_vector_type(8)));
typedef float f32x4 __attribute__((ext_vector_type(4)));

__device__ __forceinline__ unsigned short f2bf(float f) {
  unsigned int u = __float_as_uint(f);
  u += 0x7fffu + ((u >> 16) & 1u);   // round-to-nearest-even
  return (unsigned short)(u >> 16);
}

__device__ __forceinline__ void async_ld16(const void* g, void* l) {
  __builtin_amdgcn_global_load_lds(
      (const __attribute__((address_space(1))) unsigned int*)g,
      (__attribute__((address_space(3))) unsigned int*)l, 16, 0, 0);
}

__device__ const float NF4_TAB[16] = {
    -1.0f, -0.6961928009986877f, -0.5250730514526367f, -0.39491748809814453f,
    -0.28444138169288635f, -0.18477343022823334f, -0.09105003625154495f, 0.0f,
    0.07958029955625534f, 0.16093020141124725f, 0.24611230194568634f,
    0.33791524171829224f, 0.44070982933044434f, 0.5626170039176941f,
    0.7229568362236023f, 1.0f};

// ---------------- K1: x -> bf16 A', fused lora_down t = x @ Ld^T ----------------
// Block = 256 thr (4 waves), handles 4 token rows. Wave w owns ranks [4w, 4w+4).
__global__ __launch_bounds__(256) void k_prep_a(
    const float* __restrict__ x, const float* __restrict__ ldw,
    unsigned short* __restrict__ Ap) {
  const int tid = threadIdx.x;
  const int lane = tid & 63;
  const int w = tid >> 6;
  const int m0 = blockIdx.x * 4;

  float acc[4][4];
#pragma unroll
  for (int i = 0; i < 4; ++i)
#pragma unroll
    for (int rl = 0; rl < 4; ++rl) acc[i][rl] = 0.f;

  for (int c = 0; c < 16; ++c) {
    const int k0 = (c * 64 + lane) * 4;
    float4 xv[4];
#pragma unroll
    for (int i = 0; i < 4; ++i) {
      xv[i] = *(const float4*)&x[(size_t)(m0 + i) * IN_F + k0];
      if (w == 0) {  // wave 0 writes the bf16 conversion
        ushort4 s;
        s.x = f2bf(xv[i].x); s.y = f2bf(xv[i].y);
        s.z = f2bf(xv[i].z); s.w = f2bf(xv[i].w);
        *(ushort4*)&Ap[(size_t)(m0 + i) * KP + k0] = s;
      }
    }
#pragma unroll
    for (int rl = 0; rl < 4; ++rl) {
      float4 lv = *(const float4*)&ldw[(size_t)(w * 4 + rl) * IN_F + k0];
#pragma unroll
      for (int i = 0; i < 4; ++i)
        acc[i][rl] += xv[i].x * lv.x + xv[i].y * lv.y + xv[i].z * lv.z +
                      xv[i].w * lv.w;
    }
  }
  // wave-wide butterfly reduce each of the 16 partials
#pragma unroll
  for (int i = 0; i < 4; ++i)
#pragma unroll
    for (int rl = 0; rl < 4; ++rl) {
      float v = acc[i][rl];
#pragma unroll
      for (int m = 1; m < 64; m <<= 1) v += __shfl_xor(v, m, 64);
      acc[i][rl] = v;
    }
  __shared__ float red[4][16];
  if (lane == 0) {
#pragma unroll
    for (int i = 0; i < 4; ++i)
#pragma unroll
      for (int rl = 0; rl < 4; ++rl) red[i][w * 4 + rl] = acc[i][rl];
  }
  __syncthreads();
  if (tid < 64) {  // write t (bf16) into lora columns
    Ap[(size_t)(m0 + (tid >> 4)) * KP + IN_F + (tid & 15)] =
        f2bf(red[tid >> 4][tid & 15]);
  } else if (tid < 128) {  // zero pad cols 4112..4127
    const int t2 = tid - 64;
    Ap[(size_t)(m0 + (t2 >> 4)) * KP + IN_F + 16 + (t2 & 15)] = 0;
  }
}

// ---------------- K2: NF4 dequant -> bf16 B', append Lu*(alpha/r) ----------------
__global__ __launch_bounds__(256) void k_prep_b(
    const int* __restrict__ q, const float* __restrict__ amax,
    const float* __restrict__ luw, const float* __restrict__ alpha,
    unsigned short* __restrict__ Bp) {
  __shared__ float tab[16];
  const int tid = threadIdx.x;
  const int n = blockIdx.x;
  if (tid < 16) tab[tid] = NF4_TAB[tid];
  __syncthreads();
#pragma unroll
  for (int c = 0; c < 4; ++c) {
    const int k0 = (tid + 256 * c) * 4;
    int4 qv = *(const int4*)&q[(size_t)n * IN_F + k0];
    float am = amax[n * (IN_F / 64) + (k0 >> 6)];
    ushort4 s;
    s.x = f2bf(tab[qv.x] * am);
    s.y = f2bf(tab[qv.y] * am);
    s.z = f2bf(tab[qv.z] * am);
    s.w = f2bf(tab[qv.w] * am);
    *(ushort4*)&Bp[(size_t)n * KP + k0] = s;
  }
  if (tid < RANK) {
    float sc = alpha[0] * (1.0f / RANK);
    Bp[(size_t)n * KP + IN_F + tid] = f2bf(luw[n * RANK + tid] * sc);
  } else if (tid < 2 * RANK) {   // cols 4112..4127 = 0
    Bp[(size_t)n * KP + IN_F + tid] = 0;
  }
}

// ---------------- K3: 128x128 bf16 MFMA GEMM (m97 structure) ----------------
// C[m,n] = sum_k A'[m,k] * B'[n,k] + bias[n]
__global__ __launch_bounds__(256) void k_gemm(
    const unsigned short* __restrict__ Ap, const unsigned short* __restrict__ Bp,
    const float* __restrict__ bias, float* __restrict__ out) {
  __shared__ unsigned short As[2][128 * 32];
  __shared__ unsigned short Bs[2][128 * 32];
  const int tid = threadIdx.x;
  const int lane = tid & 63;
  const int wid = tid >> 6;
  const int m0 = blockIdx.y * 128;
  const int n0 = blockIdx.x * 128;
  const int wr = wid >> 1, wc = wid & 1;

  f32x4 acc[4][4] = {};

  const int srow = lane >> 2;        // 0..15
  const int scol = (lane & 3) * 8;   // element col 0,8,16,24

  // prologue: stage tile 0 into buf 0
#pragma unroll
  for (int i = 0; i < 2; ++i) {
    const int idx = wid * 2 + i;
    async_ld16(&Ap[(size_t)(m0 + idx * 16 + srow) * KP + scol], &As[0][idx * 512]);
    async_ld16(&Bp[(size_t)(n0 + idx * 16 + srow) * KP + scol], &Bs[0][idx * 512]);
  }
  __syncthreads();

  int buf = 0;
  for (int t = 0; t < NKSTEP; ++t) {
    if (t < NKSTEP - 1) {
      const int k0 = (t + 1) * 32;
#pragma unroll
      for (int i = 0; i < 2; ++i) {
        const int idx = wid * 2 + i;
        async_ld16(&Ap[(size_t)(m0 + idx * 16 + srow) * KP + k0 + scol],
                   &As[buf ^ 1][idx * 512]);
        async_ld16(&Bp[(size_t)(n0 + idx * 16 + srow) * KP + k0 + scol],
                   &Bs[buf ^ 1][idx * 512]);
      }
    }
    bf16x8 af[4], bfv[4];
#pragma unroll
    for (int i = 0; i < 4; ++i) {
      af[i] = *(const bf16x8*)&As[buf][(wr * 64 + i * 16 + (lane & 15)) * 32 +
                                       (lane >> 4) * 8];
      bfv[i] = *(const bf16x8*)&Bs[buf][(wc * 64 + i * 16 + (lane & 15)) * 32 +
                                        (lane >> 4) * 8];
    }
#pragma unroll
    for (int i = 0; i < 4; ++i)
#pragma unroll
      for (int j = 0; j < 4; ++j)
        acc[i][j] =
            __builtin_amdgcn_mfma_f32_16x16x32_bf16(af[i], bfv[j], acc[i][j], 0, 0, 0);
    __syncthreads();
    buf ^= 1;
  }

  // epilogue: bias + store (C/D layout: col = lane&15, row = (lane>>4)*4 + e)
  const int col_l = lane & 15;
  const int row_g = lane >> 4;
#pragma unroll
  for (int j = 0; j < 4; ++j) {
    const int n = n0 + wc * 64 + j * 16 + col_l;
    const float bv = bias[n];
#pragma unroll
    for (int i = 0; i < 4; ++i) {
      const int mbase = m0 + wr * 64 + i * 16 + row_g * 4;
#pragma unroll
      for (int e = 0; e < 4; ++e)
        out[(size_t)(mbase + e) * OUT_F + n] = acc[i][j][e] + bv;
    }
  }
}

extern "C" void kernel_launch(void* const* d_in, const int* in_sizes, int n_in,
                              void* d_out, int out_size, void* d_ws, size_t ws_size,
                              hipStream_t stream) {
  (void)in_sizes; (void)n_in; (void)out_size; (void)ws_size;
  const float* x     = (const float*)d_in[0];
  const float* amax  = (const float*)d_in[1];
  const float* bias  = (const float*)d_in[2];
  const float* ldw   = (const float*)d_in[3];
  const float* luw   = (const float*)d_in[4];
  const float* alpha = (const float*)d_in[5];
  const int*   q     = (const int*)d_in[6];
  float* out = (float*)d_out;

  unsigned short* Ap = (unsigned short*)d_ws;                 // [NTOK][KP] bf16
  unsigned short* Bp = Ap + (size_t)NTOK * KP;                // [OUT_F][KP] bf16

  k_prep_a<<<NTOK / 4, 256, 0, stream>>>(x, ldw, Ap);
  k_prep_b<<<OUT_F, 256, 0, stream>>>(q, amax, luw, alpha, Bp);
  k_gemm<<<dim3(OUT_F / 128, NTOK / 128), 256, 0, stream>>>(Ap, Bp, bias, out);
}

// Round 2
// 365.138 us; speedup vs baseline: 1.6096x; 1.6096x over previous
//
#include <hip/hip_runtime.h>

#define IN_F 4096
#define OUT_F 4096
#define RANK 16
#define NTOK 8192
#define KP 4160            // IN_F + 16 lora cols + 48 zero pad = 65 * 64
#define BK 64
#define NT (KP / BK)       // 65
#define BM 256
#define BN 256

typedef __bf16 bf16x8 __attribute__((ext_vector_type(8)));
typedef float f32x4 __attribute__((ext_vector_type(4)));

__device__ __forceinline__ unsigned short f2bf(float f) {
  unsigned int u = __float_as_uint(f);
  u += 0x7fffu + ((u >> 16) & 1u);   // round-to-nearest-even
  return (unsigned short)(u >> 16);
}

__device__ __forceinline__ void async_ld16(const void* g, void* l) {
  __builtin_amdgcn_global_load_lds(
      (const __attribute__((address_space(1))) unsigned int*)g,
      (__attribute__((address_space(3))) unsigned int*)l, 16, 0, 0);
}

__device__ const float NF4_TAB[16] = {
    -1.0f, -0.6961928009986877f, -0.5250730514526367f, -0.39491748809814453f,
    -0.28444138169288635f, -0.18477343022823334f, -0.09105003625154495f, 0.0f,
    0.07958029955625534f, 0.16093020141124725f, 0.24611230194568634f,
    0.33791524171829224f, 0.44070982933044434f, 0.5626170039176941f,
    0.7229568362236023f, 1.0f};

// ---------------- K1: x -> bf16 A', fused lora_down t = x @ Ld^T ----------------
__global__ __launch_bounds__(256) void k_prep_a(
    const float* __restrict__ x, const float* __restrict__ ldw,
    unsigned short* __restrict__ Ap) {
  const int tid = threadIdx.x;
  const int lane = tid & 63;
  const int w = tid >> 6;
  const int m0 = blockIdx.x * 4;

  float acc[4][4];
#pragma unroll
  for (int i = 0; i < 4; ++i)
#pragma unroll
    for (int rl = 0; rl < 4; ++rl) acc[i][rl] = 0.f;

  for (int c = 0; c < 16; ++c) {
    const int k0 = (c * 64 + lane) * 4;
    float4 xv[4];
#pragma unroll
    for (int i = 0; i < 4; ++i) {
      xv[i] = *(const float4*)&x[(size_t)(m0 + i) * IN_F + k0];
      if (w == 0) {
        ushort4 s;
        s.x = f2bf(xv[i].x); s.y = f2bf(xv[i].y);
        s.z = f2bf(xv[i].z); s.w = f2bf(xv[i].w);
        *(ushort4*)&Ap[(size_t)(m0 + i) * KP + k0] = s;
      }
    }
#pragma unroll
    for (int rl = 0; rl < 4; ++rl) {
      float4 lv = *(const float4*)&ldw[(size_t)(w * 4 + rl) * IN_F + k0];
#pragma unroll
      for (int i = 0; i < 4; ++i)
        acc[i][rl] += xv[i].x * lv.x + xv[i].y * lv.y + xv[i].z * lv.z +
                      xv[i].w * lv.w;
    }
  }
#pragma unroll
  for (int i = 0; i < 4; ++i)
#pragma unroll
    for (int rl = 0; rl < 4; ++rl) {
      float v = acc[i][rl];
#pragma unroll
      for (int m = 1; m < 64; m <<= 1) v += __shfl_xor(v, m, 64);
      acc[i][rl] = v;
    }
  __shared__ float red[4][16];
  if (lane == 0) {
#pragma unroll
    for (int i = 0; i < 4; ++i)
#pragma unroll
      for (int rl = 0; rl < 4; ++rl) red[i][w * 4 + rl] = acc[i][rl];
  }
  __syncthreads();
  if (tid < 64) {  // lora columns 4096..4111
    Ap[(size_t)(m0 + (tid >> 4)) * KP + IN_F + (tid & 15)] =
        f2bf(red[tid >> 4][tid & 15]);
  } else {  // zero pad cols 4112..4159 : 4 rows x 48 cols = 192 elems
    const int t2 = tid - 64;
    if (t2 < 192)
      Ap[(size_t)(m0 + t2 / 48) * KP + IN_F + 16 + (t2 % 48)] = 0;
  }
}

// ---------------- K2: NF4 dequant -> bf16 B', append Lu*(alpha/r) ----------------
__global__ __launch_bounds__(256) void k_prep_b(
    const int* __restrict__ q, const float* __restrict__ amax,
    const float* __restrict__ luw, const float* __restrict__ alpha,
    unsigned short* __restrict__ Bp) {
  __shared__ float tab[16];
  const int tid = threadIdx.x;
  const int n = blockIdx.x;
  if (tid < 16) tab[tid] = NF4_TAB[tid];
  __syncthreads();
#pragma unroll
  for (int c = 0; c < 4; ++c) {
    const int k0 = (tid + 256 * c) * 4;
    int4 qv = *(const int4*)&q[(size_t)n * IN_F + k0];
    float am = amax[n * (IN_F / 64) + (k0 >> 6)];
    ushort4 s;
    s.x = f2bf(tab[qv.x] * am);
    s.y = f2bf(tab[qv.y] * am);
    s.z = f2bf(tab[qv.z] * am);
    s.w = f2bf(tab[qv.w] * am);
    *(ushort4*)&Bp[(size_t)n * KP + k0] = s;
  }
  if (tid < RANK) {
    float sc = alpha[0] * (1.0f / RANK);
    Bp[(size_t)n * KP + IN_F + tid] = f2bf(luw[n * RANK + tid] * sc);
  } else if (tid < 64) {  // zero pad cols 4112..4159
    Bp[(size_t)n * KP + IN_F + tid] = 0;
  }
}

// ---------------- K3: 256x256 8-phase bf16 MFMA GEMM (m201 template) ----------------
// C[m,n] = sum_k A'[m,k] * B'[n,k] + bias[n]
// 8 waves = 2M x 4N, per-wave 128x64 output, BK=64, 2 LDS buffers of
// {A[2x128x64], B[2x128x64]} bf16 = 128 KiB. st_16x32 swizzle:
// byte ^= ((byte>>9)&1)<<5 within each 16KB half-tile (involution applied on
// the global-load SOURCE and on ds_read addresses; LDS dest stays linear).
__global__ __launch_bounds__(512, 1) void k_gemm(
    const unsigned short* __restrict__ Ap, const unsigned short* __restrict__ Bp,
    const float* __restrict__ bias, float* __restrict__ out) {
  __shared__ unsigned short lds[65536];  // 128 KiB
  const int tid = threadIdx.x;
  const int lane = tid & 63;
  const int w = tid >> 6;
  const int wr = w >> 2;       // 0..1
  const int wc = w & 3;        // 0..3
  const int m0 = blockIdx.y * BM;
  const int n0 = blockIdx.x * BN;

  // staging: per half-tile [128][64]: wave w covers rows w*16+i*8+(lane>>3)
  // source col pre-swizzled (inverse of read swizzle)
  const int scol = ((lane & 7) << 3) ^ ((lane >> 5) << 4);   // bf16 elems
  const unsigned short* gA = Ap + (size_t)(m0 + (w << 4) + (lane >> 3)) * KP + scol;
  const unsigned short* gB = Bp + (size_t)(n0 + (w << 4) + (lane >> 3)) * KP + scol;
  unsigned short* const ldsw = lds + (w << 10);  // wave-uniform dest base (shorts)

  // ds_read per-thread offset within half-tile (shorts), swizzled
  const int rdoff =
      ((lane & 15) << 6) + ((((lane >> 4) << 3)) ^ (((lane >> 2) & 1) << 4));

#define STAGE2(tt, ht, cond)                                                   \
  if (cond) {                                                                  \
    const unsigned short* s_ =                                                 \
        ((ht) < 2 ? gA + (size_t)((ht) << 7) * KP                              \
                  : gB + (size_t)(((ht)-2) << 7) * KP) + (size_t)(tt)*BK;      \
    unsigned short* d_ = ldsw + ((((tt)&1) << 15) + ((ht) << 13));             \
    async_ld16(s_, d_);                                                        \
    async_ld16(s_ + (size_t)8 * KP, d_ + 512);                                 \
  }

#define LDA(bsel, mh, f, kc)                                                   \
  (*(const bf16x8*)&lds[((bsel) << 15) + (wr << 13) +                          \
                        (((mh)*64 + (f)*16) << 6) + ((kc) << 5) + rdoff])
#define LDB(bsel, nh, g, kc)                                                   \
  (*(const bf16x8*)&lds[((bsel) << 15) + ((2 + (wc >> 1)) << 13) +             \
                        ((((wc & 1) * 64) + (nh)*32 + (g)*16) << 6) +          \
                        ((kc) << 5) + rdoff])

#define MFMA(a, b, c) __builtin_amdgcn_mfma_f32_16x16x32_bf16((a), (b), (c), 0, 0, 0)

  // ---- prologue: tile0 all 4 half-tiles, tile1 first 3; counted drains ----
  STAGE2(0, 0, true) STAGE2(0, 1, true) STAGE2(0, 2, true) STAGE2(0, 3, true)
  asm volatile("s_waitcnt vmcnt(4)" ::: "memory");
  STAGE2(1, 0, true) STAGE2(1, 1, true) STAGE2(1, 2, true)
  asm volatile("s_waitcnt vmcnt(6)" ::: "memory");
  __builtin_amdgcn_s_barrier();

  f32x4 acc[8][4] = {};
  bf16x8 a0[4][2], a1[4][2], bq[2][2];

#pragma unroll 2
  for (int t = 0; t < NT; ++t) {
    const int bsel = t & 1;
    // ---------- phase 0: quadrant (M0,N0); read a0 + b(N0); stage B-hi(t+1) ----
#pragma unroll
    for (int f = 0; f < 4; ++f) {
      a0[f][0] = LDA(bsel, 0, f, 0);
      a0[f][1] = LDA(bsel, 0, f, 1);
    }
#pragma unroll
    for (int g = 0; g < 2; ++g) {
      bq[g][0] = LDB(bsel, 0, g, 0);
      bq[g][1] = LDB(bsel, 0, g, 1);
    }
    STAGE2(t + 1, 3, t + 1 < NT)
    __builtin_amdgcn_s_barrier();
    asm volatile("s_waitcnt lgkmcnt(0)" ::: "memory");
    __builtin_amdgcn_sched_barrier(0);
    __builtin_amdgcn_s_setprio(1);
#pragma unroll
    for (int f = 0; f < 4; ++f)
#pragma unroll
      for (int g = 0; g < 2; ++g) {
        acc[f][g] = MFMA(a0[f][0], bq[g][0], acc[f][g]);
        acc[f][g] = MFMA(a0[f][1], bq[g][1], acc[f][g]);
      }
    __builtin_amdgcn_s_setprio(0);
    __builtin_amdgcn_s_barrier();
    // ---------- phase 1: quadrant (M1,N0); read a1; stage A-lo(t+2) ----------
#pragma unroll
    for (int f = 0; f < 4; ++f) {
      a1[f][0] = LDA(bsel, 1, f, 0);
      a1[f][1] = LDA(bsel, 1, f, 1);
    }
    STAGE2(t + 2, 0, t + 2 < NT)
    __builtin_amdgcn_s_barrier();
    asm volatile("s_waitcnt lgkmcnt(0)" ::: "memory");
    __builtin_amdgcn_sched_barrier(0);
    __builtin_amdgcn_s_setprio(1);
#pragma unroll
    for (int f = 0; f < 4; ++f)
#pragma unroll
      for (int g = 0; g < 2; ++g) {
        acc[4 + f][g] = MFMA(a1[f][0], bq[g][0], acc[4 + f][g]);
        acc[4 + f][g] = MFMA(a1[f][1], bq[g][1], acc[4 + f][g]);
      }
    __builtin_amdgcn_s_setprio(0);
    __builtin_amdgcn_s_barrier();
    // ---------- phase 2: quadrant (M1,N1); read b(N1); stage A-hi(t+2) -------
#pragma unroll
    for (int g = 0; g < 2; ++g) {
      bq[g][0] = LDB(bsel, 1, g, 0);
      bq[g][1] = LDB(bsel, 1, g, 1);
    }
    STAGE2(t + 2, 1, t + 2 < NT)
    __builtin_amdgcn_s_barrier();
    asm volatile("s_waitcnt lgkmcnt(0)" ::: "memory");
    __builtin_amdgcn_sched_barrier(0);
    __builtin_amdgcn_s_setprio(1);
#pragma unroll
    for (int f = 0; f < 4; ++f)
#pragma unroll
      for (int g = 0; g < 2; ++g) {
        acc[4 + f][2 + g] = MFMA(a1[f][0], bq[g][0], acc[4 + f][2 + g]);
        acc[4 + f][2 + g] = MFMA(a1[f][1], bq[g][1], acc[4 + f][2 + g]);
      }
    __builtin_amdgcn_s_setprio(0);
    __builtin_amdgcn_s_barrier();
    // ---------- phase 3: quadrant (M0,N1); reuse a0,b; stage B-lo(t+2) -------
    STAGE2(t + 2, 2, t + 2 < NT)
    __builtin_amdgcn_s_barrier();
    asm volatile("s_waitcnt lgkmcnt(0)" ::: "memory");
    __builtin_amdgcn_sched_barrier(0);
    __builtin_amdgcn_s_setprio(1);
#pragma unroll
    for (int f = 0; f < 4; ++f)
#pragma unroll
      for (int g = 0; g < 2; ++g) {
        acc[f][2 + g] = MFMA(a0[f][0], bq[g][0], acc[f][2 + g]);
        acc[f][2 + g] = MFMA(a0[f][1], bq[g][1], acc[f][2 + g]);
      }
    __builtin_amdgcn_s_setprio(0);
    // counted drain: keep 3 half-tiles (6 loads) in flight; full drain only
    // when the pipeline is ending.
    if (t < NT - 2) {
      asm volatile("s_waitcnt vmcnt(6)" ::: "memory");
    } else if (t == NT - 2) {
      asm volatile("s_waitcnt vmcnt(0)" ::: "memory");
    }
    __builtin_amdgcn_s_barrier();
    __builtin_amdgcn_sched_barrier(0);
  }

  // ---- epilogue: bias + f32 store (C/D: col = lane&15, row = (lane>>4)*4+e) ----
  const int colL = lane & 15;
  const int rowG = lane >> 4;
#pragma unroll
  for (int nj = 0; nj < 4; ++nj) {
    const int n = n0 + wc * 64 + nj * 16 + colL;
    const float bv = bias[n];
#pragma unroll
    for (int mi = 0; mi < 8; ++mi) {
      const int mb = m0 + wr * 128 + mi * 16 + rowG * 4;
#pragma unroll
      for (int e = 0; e < 4; ++e)
        out[(size_t)(mb + e) * OUT_F + n] = acc[mi][nj][e] + bv;
    }
  }
#undef STAGE2
#undef LDA
#undef LDB
#undef MFMA
}

extern "C" void kernel_launch(void* const* d_in, const int* in_sizes, int n_in,
                              void* d_out, int out_size, void* d_ws, size_t ws_size,
                              hipStream_t stream) {
  (void)in_sizes; (void)n_in; (void)out_size; (void)ws_size;
  const float* x     = (const float*)d_in[0];
  const float* amax  = (const float*)d_in[1];
  const float* bias  = (const float*)d_in[2];
  const float* ldw   = (const float*)d_in[3];
  const float* luw   = (const float*)d_in[4];
  const float* alpha = (const float*)d_in[5];
  const int*   q     = (const int*)d_in[6];
  float* out = (float*)d_out;

  unsigned short* Ap = (unsigned short*)d_ws;                 // [NTOK][KP] bf16
  unsigned short* Bp = Ap + (size_t)NTOK * KP;                // [OUT_F][KP] bf16

  k_prep_a<<<NTOK / 4, 256, 0, stream>>>(x, ldw, Ap);
  k_prep_b<<<OUT_F, 256, 0, stream>>>(q, amax, luw, alpha, Bp);
  k_gemm<<<dim3(OUT_F / BN, NTOK / BM), 512, 0, stream>>>(Ap, Bp, bias, out);
}

// Round 3
// 351.286 us; speedup vs baseline: 1.6731x; 1.0394x over previous
//
#include <hip/hip_runtime.h>

#define IN_F 4096
#define OUT_F 4096
#define RANK 16
#define NTOK 8192
#define KP 4160            // IN_F + 16 lora cols + 48 zero pad = 65 * 64
#define BK 64
#define NT (KP / BK)       // 65
#define BM 256
#define BN 256

typedef __bf16 bf16x8 __attribute__((ext_vector_type(8)));
typedef float f32x4 __attribute__((ext_vector_type(4)));

__device__ __forceinline__ unsigned short f2bf(float f) {
  unsigned int u = __float_as_uint(f);
  u += 0x7fffu + ((u >> 16) & 1u);   // round-to-nearest-even
  return (unsigned short)(u >> 16);
}

__device__ __forceinline__ void async_ld16(const void* g, void* l) {
  __builtin_amdgcn_global_load_lds(
      (const __attribute__((address_space(1))) unsigned int*)g,
      (__attribute__((address_space(3))) unsigned int*)l, 16, 0, 0);
}

__device__ const float NF4_TAB[16] = {
    -1.0f, -0.6961928009986877f, -0.5250730514526367f, -0.39491748809814453f,
    -0.28444138169288635f, -0.18477343022823334f, -0.09105003625154495f, 0.0f,
    0.07958029955625534f, 0.16093020141124725f, 0.24611230194568634f,
    0.33791524171829224f, 0.44070982933044434f, 0.5626170039176941f,
    0.7229568362236023f, 1.0f};

// ---------------- K1: x -> bf16 A', fused lora_down t = x @ Ld^T ----------------
__global__ __launch_bounds__(256) void k_prep_a(
    const float* __restrict__ x, const float* __restrict__ ldw,
    unsigned short* __restrict__ Ap) {
  const int tid = threadIdx.x;
  const int lane = tid & 63;
  const int w = tid >> 6;
  const int m0 = blockIdx.x * 4;

  float acc[4][4];
#pragma unroll
  for (int i = 0; i < 4; ++i)
#pragma unroll
    for (int rl = 0; rl < 4; ++rl) acc[i][rl] = 0.f;

  for (int c = 0; c < 16; ++c) {
    const int k0 = (c * 64 + lane) * 4;
    float4 xv[4];
#pragma unroll
    for (int i = 0; i < 4; ++i) {
      xv[i] = *(const float4*)&x[(size_t)(m0 + i) * IN_F + k0];
      if (w == 0) {
        ushort4 s;
        s.x = f2bf(xv[i].x); s.y = f2bf(xv[i].y);
        s.z = f2bf(xv[i].z); s.w = f2bf(xv[i].w);
        *(ushort4*)&Ap[(size_t)(m0 + i) * KP + k0] = s;
      }
    }
#pragma unroll
    for (int rl = 0; rl < 4; ++rl) {
      float4 lv = *(const float4*)&ldw[(size_t)(w * 4 + rl) * IN_F + k0];
#pragma unroll
      for (int i = 0; i < 4; ++i)
        acc[i][rl] += xv[i].x * lv.x + xv[i].y * lv.y + xv[i].z * lv.z +
                      xv[i].w * lv.w;
    }
  }
#pragma unroll
  for (int i = 0; i < 4; ++i)
#pragma unroll
    for (int rl = 0; rl < 4; ++rl) {
      float v = acc[i][rl];
#pragma unroll
      for (int m = 1; m < 64; m <<= 1) v += __shfl_xor(v, m, 64);
      acc[i][rl] = v;
    }
  __shared__ float red[4][16];
  if (lane == 0) {
#pragma unroll
    for (int i = 0; i < 4; ++i)
#pragma unroll
      for (int rl = 0; rl < 4; ++rl) red[i][w * 4 + rl] = acc[i][rl];
  }
  __syncthreads();
  if (tid < 64) {  // lora columns 4096..4111
    Ap[(size_t)(m0 + (tid >> 4)) * KP + IN_F + (tid & 15)] =
        f2bf(red[tid >> 4][tid & 15]);
  } else {  // zero pad cols 4112..4159 : 4 rows x 48 cols = 192 elems
    const int t2 = tid - 64;
    if (t2 < 192)
      Ap[(size_t)(m0 + t2 / 48) * KP + IN_F + 16 + (t2 % 48)] = 0;
  }
}

// ---------------- K2: NF4 dequant -> bf16 B', append Lu*(alpha/r) ----------------
__global__ __launch_bounds__(256) void k_prep_b(
    const int* __restrict__ q, const float* __restrict__ amax,
    const float* __restrict__ luw, const float* __restrict__ alpha,
    unsigned short* __restrict__ Bp) {
  __shared__ float tab[16];
  const int tid = threadIdx.x;
  const int n = blockIdx.x;
  if (tid < 16) tab[tid] = NF4_TAB[tid];
  __syncthreads();
#pragma unroll
  for (int c = 0; c < 4; ++c) {
    const int k0 = (tid + 256 * c) * 4;
    int4 qv = *(const int4*)&q[(size_t)n * IN_F + k0];
    float am = amax[n * (IN_F / 64) + (k0 >> 6)];
    ushort4 s;
    s.x = f2bf(tab[qv.x] * am);
    s.y = f2bf(tab[qv.y] * am);
    s.z = f2bf(tab[qv.z] * am);
    s.w = f2bf(tab[qv.w] * am);
    *(ushort4*)&Bp[(size_t)n * KP + k0] = s;
  }
  if (tid < RANK) {
    float sc = alpha[0] * (1.0f / RANK);
    Bp[(size_t)n * KP + IN_F + tid] = f2bf(luw[n * RANK + tid] * sc);
  } else if (tid < 64) {  // zero pad cols 4112..4159
    Bp[(size_t)n * KP + IN_F + tid] = 0;
  }
}

// ---------------- K3: 256x256 8-phase bf16 MFMA GEMM ----------------
// C[m,n] = sum_k A'[m,k] * B'[n,k] + bias[n]
// 8 waves = 2M x 4N, per-wave 128x64 output, BK=64.
// LDS: 2 dbuf x 4 half-tiles [128][64] bf16 = 128 KiB.
// T2 swizzle (3-bit, 16B-slot granularity): LDS holds global slot
// (slot_lds ^ (row&7)); staging source pre-applies the involution, reads
// re-apply it. Stage schedule is race-clean: same-buffer staging only in a
// phase strictly after that region's last read barrier.
__global__ __launch_bounds__(512, 1) void k_gemm(
    const unsigned short* __restrict__ Ap, const unsigned short* __restrict__ Bp,
    const float* __restrict__ bias, float* __restrict__ out) {
  __shared__ unsigned short lds[65536];  // 128 KiB
  const int tid = threadIdx.x;
  const int lane = tid & 63;
  const int w = tid >> 6;
  const int wr = w >> 2;       // 0..1
  const int wc = w & 3;        // 0..3

  // T1: XCD-aware block swizzle (nwg = 512, divisible by 8)
  const int nwg = gridDim.x * gridDim.y;           // 512
  const int flat = blockIdx.y * gridDim.x + blockIdx.x;
  const int cpx = nwg >> 3;
  const int swz = (flat & 7) * cpx + (flat >> 3);
  const int m0 = (swz / (OUT_F / BN)) * BM;
  const int n0 = (swz % (OUT_F / BN)) * BN;

  // staging: wave w covers half-tile rows w*16 + i*8 + (lane>>3), i=0,1
  // source col slot pre-swizzled: slot_src = (lane&7) ^ (row&7), row&7 = lane>>3
  const int srow = lane >> 3;                       // 0..7
  const int scol = (((lane & 7) ^ srow) << 3);      // bf16 elems
  const unsigned short* gA = Ap + (size_t)(m0 + (w << 4) + srow) * KP + scol;
  const unsigned short* gB = Bp + (size_t)(n0 + (w << 4) + srow) * KP + scol;
  unsigned short* const ldsw = lds + (w << 10);     // wave-uniform dest base

  // read offset: row = lane&15 (row&7 = lane&7), col slot = (lane>>4) ^ (lane&7);
  // kc selects slot bit 2 via XOR (rdoff ^ (kc<<5))
  const int rdoff = ((lane & 15) << 6) + (((lane >> 4) ^ (lane & 7)) << 3);

#define STAGE2(tt, ht, cond)                                                   \
  if (cond) {                                                                  \
    const unsigned short* s_ =                                                 \
        ((ht) < 2 ? gA + (size_t)((ht) << 7) * KP                              \
                  : gB + (size_t)(((ht)-2) << 7) * KP) + (size_t)(tt)*BK;      \
    unsigned short* d_ = ldsw + ((((tt)&1) << 15) + ((ht) << 13));             \
    async_ld16(s_, d_);                                                        \
    async_ld16(s_ + (size_t)8 * KP, d_ + 512);                                 \
  }

#define LDA(bsel, mh, f, kc)                                                   \
  (*(const bf16x8*)&lds[((bsel) << 15) + (wr << 13) +                          \
                        (((mh)*64 + (f)*16) << 6) + (((kc) << 5) ^ rdoff)])
#define LDB(bsel, nh, g, kc)                                                   \
  (*(const bf16x8*)&lds[((bsel) << 15) + ((2 + (wc >> 1)) << 13) +             \
                        ((((wc & 1) * 64) + (nh)*32 + (g)*16) << 6) +          \
                        (((kc) << 5) ^ rdoff)])

#define MFMA(a, b, c) __builtin_amdgcn_mfma_f32_16x16x32_bf16((a), (b), (c), 0, 0, 0)

  // ---- prologue: tile0 (all 4 half-tiles) + tile1 A half-tiles ----
  STAGE2(0, 0, true) STAGE2(0, 1, true) STAGE2(0, 2, true) STAGE2(0, 3, true)
  STAGE2(1, 0, true) STAGE2(1, 1, true)
  asm volatile("s_waitcnt vmcnt(4)" ::: "memory");   // tile0 fully landed
  __builtin_amdgcn_s_barrier();

  f32x4 acc[8][4] = {};
  bf16x8 a0[4][2], a1[4][2], bq[2][2];

#pragma unroll 2
  for (int t = 0; t < NT; ++t) {
    const int bsel = t & 1;
    // ---------- phase 0: quadrant (M0,N0); read a0 + b(N0); stage B2(t+1) ----
#pragma unroll
    for (int f = 0; f < 4; ++f) {
      a0[f][0] = LDA(bsel, 0, f, 0);
      a0[f][1] = LDA(bsel, 0, f, 1);
    }
#pragma unroll
    for (int g = 0; g < 2; ++g) {
      bq[g][0] = LDB(bsel, 0, g, 0);
      bq[g][1] = LDB(bsel, 0, g, 1);
    }
    STAGE2(t + 1, 2, t + 1 < NT)
    __builtin_amdgcn_s_barrier();
    asm volatile("s_waitcnt lgkmcnt(0)" ::: "memory");
    __builtin_amdgcn_sched_barrier(0);
    __builtin_amdgcn_s_setprio(1);
#pragma unroll
    for (int f = 0; f < 4; ++f)
#pragma unroll
      for (int g = 0; g < 2; ++g) {
        acc[f][g] = MFMA(a0[f][0], bq[g][0], acc[f][g]);
        acc[f][g] = MFMA(a0[f][1], bq[g][1], acc[f][g]);
      }
    __builtin_amdgcn_s_setprio(0);
    __builtin_amdgcn_s_barrier();
    // ---------- phase 1: quadrant (M1,N0); read a1; stage B3(t+1) ----------
#pragma unroll
    for (int f = 0; f < 4; ++f) {
      a1[f][0] = LDA(bsel, 1, f, 0);
      a1[f][1] = LDA(bsel, 1, f, 1);
    }
    STAGE2(t + 1, 3, t + 1 < NT)
    __builtin_amdgcn_s_barrier();
    asm volatile("s_waitcnt lgkmcnt(0)" ::: "memory");
    __builtin_amdgcn_sched_barrier(0);
    __builtin_amdgcn_s_setprio(1);
#pragma unroll
    for (int f = 0; f < 4; ++f)
#pragma unroll
      for (int g = 0; g < 2; ++g) {
        acc[4 + f][g] = MFMA(a1[f][0], bq[g][0], acc[4 + f][g]);
        acc[4 + f][g] = MFMA(a1[f][1], bq[g][1], acc[4 + f][g]);
      }
    __builtin_amdgcn_s_setprio(0);
    __builtin_amdgcn_s_barrier();
    // ---------- phase 2: quadrant (M1,N1); read b(N1); stage A0(t+2) -------
    // (A reads of this buffer completed at phase-1-end barrier)
#pragma unroll
    for (int g = 0; g < 2; ++g) {
      bq[g][0] = LDB(bsel, 1, g, 0);
      bq[g][1] = LDB(bsel, 1, g, 1);
    }
    STAGE2(t + 2, 0, t + 2 < NT)
    __builtin_amdgcn_s_barrier();
    asm volatile("s_waitcnt lgkmcnt(0)" ::: "memory");
    __builtin_amdgcn_sched_barrier(0);
    __builtin_amdgcn_s_setprio(1);
#pragma unroll
    for (int f = 0; f < 4; ++f)
#pragma unroll
      for (int g = 0; g < 2; ++g) {
        acc[4 + f][2 + g] = MFMA(a1[f][0], bq[g][0], acc[4 + f][2 + g]);
        acc[4 + f][2 + g] = MFMA(a1[f][1], bq[g][1], acc[4 + f][2 + g]);
      }
    __builtin_amdgcn_s_setprio(0);
    __builtin_amdgcn_s_barrier();
    // ---------- phase 3: quadrant (M0,N1); reuse a0,bq; stage A1(t+2) -------
    STAGE2(t + 2, 1, t + 2 < NT)
    __builtin_amdgcn_s_barrier();
    asm volatile("s_waitcnt lgkmcnt(0)" ::: "memory");
    __builtin_amdgcn_sched_barrier(0);
    __builtin_amdgcn_s_setprio(1);
#pragma unroll
    for (int f = 0; f < 4; ++f)
#pragma unroll
      for (int g = 0; g < 2; ++g) {
        acc[f][2 + g] = MFMA(a0[f][0], bq[g][0], acc[f][2 + g]);
        acc[f][2 + g] = MFMA(a0[f][1], bq[g][1], acc[f][2 + g]);
      }
    __builtin_amdgcn_s_setprio(0);
    // counted drain: tile t+1 must be fully landed; keep A(t+2) in flight.
    if (t < NT - 2) {
      asm volatile("s_waitcnt vmcnt(4)" ::: "memory");
    } else if (t == NT - 2) {
      asm volatile("s_waitcnt vmcnt(0)" ::: "memory");
    }
    __builtin_amdgcn_s_barrier();
    __builtin_amdgcn_sched_barrier(0);
  }

  // ---- epilogue: bias + f32 store (C/D: col = lane&15, row = (lane>>4)*4+e) ----
  const int colL = lane & 15;
  const int rowG = lane >> 4;
#pragma unroll
  for (int nj = 0; nj < 4; ++nj) {
    const int n = n0 + wc * 64 + nj * 16 + colL;
    const float bv = bias[n];
#pragma unroll
    for (int mi = 0; mi < 8; ++mi) {
      const int mb = m0 + wr * 128 + mi * 16 + rowG * 4;
#pragma unroll
      for (int e = 0; e < 4; ++e)
        out[(size_t)(mb + e) * OUT_F + n] = acc[mi][nj][e] + bv;
    }
  }
#undef STAGE2
#undef LDA
#undef LDB
#undef MFMA
}

extern "C" void kernel_launch(void* const* d_in, const int* in_sizes, int n_in,
                              void* d_out, int out_size, void* d_ws, size_t ws_size,
                              hipStream_t stream) {
  (void)in_sizes; (void)n_in; (void)out_size; (void)ws_size;
  const float* x     = (const float*)d_in[0];
  const float* amax  = (const float*)d_in[1];
  const float* bias  = (const float*)d_in[2];
  const float* ldw   = (const float*)d_in[3];
  const float* luw   = (const float*)d_in[4];
  const float* alpha = (const float*)d_in[5];
  const int*   q     = (const int*)d_in[6];
  float* out = (float*)d_out;

  unsigned short* Ap = (unsigned short*)d_ws;                 // [NTOK][KP] bf16
  unsigned short* Bp = Ap + (size_t)NTOK * KP;                // [OUT_F][KP] bf16

  k_prep_a<<<NTOK / 4, 256, 0, stream>>>(x, ldw, Ap);
  k_prep_b<<<OUT_F, 256, 0, stream>>>(q, amax, luw, alpha, Bp);
  k_gemm<<<dim3(OUT_F / BN, NTOK / BM), 512, 0, stream>>>(Ap, Bp, bias, out);
}

// Round 4
// 344.500 us; speedup vs baseline: 1.7060x; 1.0197x over previous
//
#include <hip/hip_runtime.h>

#define IN_F 4096
#define OUT_F 4096
#define RANK 16
#define NTOK 8192
#define KP 4160            // IN_F + 16 lora cols + 48 zero pad = 65 * 64
#define BK 64
#define NT (KP / BK)       // 65
#define BM 256
#define BN 256

typedef __bf16 bf16x8 __attribute__((ext_vector_type(8)));
typedef float f32x4 __attribute__((ext_vector_type(4)));

__device__ __forceinline__ unsigned short f2bf(float f) {
  unsigned int u = __float_as_uint(f);
  u += 0x7fffu + ((u >> 16) & 1u);   // round-to-nearest-even
  return (unsigned short)(u >> 16);
}

__device__ __forceinline__ void async_ld16(const void* g, void* l) {
  __builtin_amdgcn_global_load_lds(
      (const __attribute__((address_space(1))) unsigned int*)g,
      (__attribute__((address_space(3))) unsigned int*)l, 16, 0, 0);
}

__device__ const float NF4_TAB[16] = {
    -1.0f, -0.6961928009986877f, -0.5250730514526367f, -0.39491748809814453f,
    -0.28444138169288635f, -0.18477343022823334f, -0.09105003625154495f, 0.0f,
    0.07958029955625534f, 0.16093020141124725f, 0.24611230194568634f,
    0.33791524171829224f, 0.44070982933044434f, 0.5626170039176941f,
    0.7229568362236023f, 1.0f};

// ---------------- K1: x -> bf16 A', fused lora_down t = x @ Ld^T ----------------
__global__ __launch_bounds__(256) void k_prep_a(
    const float* __restrict__ x, const float* __restrict__ ldw,
    unsigned short* __restrict__ Ap) {
  const int tid = threadIdx.x;
  const int lane = tid & 63;
  const int w = tid >> 6;
  const int m0 = blockIdx.x * 4;

  float acc[4][4];
#pragma unroll
  for (int i = 0; i < 4; ++i)
#pragma unroll
    for (int rl = 0; rl < 4; ++rl) acc[i][rl] = 0.f;

  for (int c = 0; c < 16; ++c) {
    const int k0 = (c * 64 + lane) * 4;
    float4 xv[4];
#pragma unroll
    for (int i = 0; i < 4; ++i) {
      xv[i] = *(const float4*)&x[(size_t)(m0 + i) * IN_F + k0];
      if (w == i) {  // wave i writes row i's bf16 conversion (balanced)
        ushort4 s;
        s.x = f2bf(xv[i].x); s.y = f2bf(xv[i].y);
        s.z = f2bf(xv[i].z); s.w = f2bf(xv[i].w);
        *(ushort4*)&Ap[(size_t)(m0 + i) * KP + k0] = s;
      }
    }
#pragma unroll
    for (int rl = 0; rl < 4; ++rl) {
      float4 lv = *(const float4*)&ldw[(size_t)(w * 4 + rl) * IN_F + k0];
#pragma unroll
      for (int i = 0; i < 4; ++i)
        acc[i][rl] += xv[i].x * lv.x + xv[i].y * lv.y + xv[i].z * lv.z +
                      xv[i].w * lv.w;
    }
  }
#pragma unroll
  for (int i = 0; i < 4; ++i)
#pragma unroll
    for (int rl = 0; rl < 4; ++rl) {
      float v = acc[i][rl];
#pragma unroll
      for (int m = 1; m < 64; m <<= 1) v += __shfl_xor(v, m, 64);
      acc[i][rl] = v;
    }
  __shared__ float red[4][16];
  if (lane == 0) {
#pragma unroll
    for (int i = 0; i < 4; ++i)
#pragma unroll
      for (int rl = 0; rl < 4; ++rl) red[i][w * 4 + rl] = acc[i][rl];
  }
  __syncthreads();
  if (tid < 64) {  // lora columns 4096..4111
    Ap[(size_t)(m0 + (tid >> 4)) * KP + IN_F + (tid & 15)] =
        f2bf(red[tid >> 4][tid & 15]);
  } else {  // zero pad cols 4112..4159 : 4 rows x 48 cols = 192 elems
    const int t2 = tid - 64;
    if (t2 < 192)
      Ap[(size_t)(m0 + t2 / 48) * KP + IN_F + 16 + (t2 % 48)] = 0;
  }
}

// ---------------- K2: NF4 dequant -> bf16 B', append Lu*(alpha/r) ----------------
__global__ __launch_bounds__(256) void k_prep_b(
    const int* __restrict__ q, const float* __restrict__ amax,
    const float* __restrict__ luw, const float* __restrict__ alpha,
    unsigned short* __restrict__ Bp) {
  __shared__ float tab[16];
  const int tid = threadIdx.x;
  const int n = blockIdx.x;
  if (tid < 16) tab[tid] = NF4_TAB[tid];
  __syncthreads();
#pragma unroll
  for (int c = 0; c < 4; ++c) {
    const int k0 = (tid + 256 * c) * 4;
    int4 qv = *(const int4*)&q[(size_t)n * IN_F + k0];
    float am = amax[n * (IN_F / 64) + (k0 >> 6)];
    ushort4 s;
    s.x = f2bf(tab[qv.x] * am);
    s.y = f2bf(tab[qv.y] * am);
    s.z = f2bf(tab[qv.z] * am);
    s.w = f2bf(tab[qv.w] * am);
    *(ushort4*)&Bp[(size_t)n * KP + k0] = s;
  }
  if (tid < RANK) {
    float sc = alpha[0] * (1.0f / RANK);
    Bp[(size_t)n * KP + IN_F + tid] = f2bf(luw[n * RANK + tid] * sc);
  } else if (tid < 64) {  // zero pad cols 4112..4159
    Bp[(size_t)n * KP + IN_F + tid] = 0;
  }
}

// ---------------- K3: 256x256 8-phase bf16 MFMA GEMM ----------------
// C[m,n] = sum_k A'[m,k] * B'[n,k] + bias[n]
// 8 waves = 2M x 4N, per-wave 128x64 output, BK=64.
// LDS: 2 dbuf x 4 half-tiles [128][64] bf16 = 128 KiB.
// T2 swizzle (3-bit, 16B-slot): LDS slot = global_slot ^ (row&7); involution
// pre-applied on staging source and on ds_read addresses (rule 21).
// Pipeline: uniformly 2 K-tiles deep. Region-race analysis:
//   A regions (ht0/ht1) of buf[p] fully read after ph1's lgkmcnt+barrier
//   B regions (ht2/ht3) of buf[p] fully read after ph2's lgkmcnt+barrier
// so ph2 stages A(t+2) and ph3 stages B(t+2); steady wait = vmcnt(8)
// (keeps the full t+2 tile, 8 loads, in flight; issue->wait = 4 phases).
__global__ __launch_bounds__(512, 1) void k_gemm(
    const unsigned short* __restrict__ Ap, const unsigned short* __restrict__ Bp,
    const float* __restrict__ bias, float* __restrict__ out) {
  __shared__ unsigned short lds[65536];  // 128 KiB
  const int tid = threadIdx.x;
  const int lane = tid & 63;
  const int w = tid >> 6;
  const int wr = w >> 2;       // 0..1
  const int wc = w & 3;        // 0..3

  // T1: XCD-aware block swizzle (nwg = 512, divisible by 8)
  const int nwg = gridDim.x * gridDim.y;           // 512
  const int flat = blockIdx.y * gridDim.x + blockIdx.x;
  const int cpx = nwg >> 3;
  const int swz = (flat & 7) * cpx + (flat >> 3);
  const int m0 = (swz / (OUT_F / BN)) * BM;
  const int n0 = (swz % (OUT_F / BN)) * BN;

  // staging: wave w covers half-tile rows w*16 + i*8 + (lane>>3), i=0,1
  // source col slot pre-swizzled: slot_src = (lane&7) ^ (row&7)
  const int srow = lane >> 3;                       // 0..7
  const int scol = (((lane & 7) ^ srow) << 3);      // bf16 elems
  const unsigned short* gA = Ap + (size_t)(m0 + (w << 4) + srow) * KP + scol;
  const unsigned short* gB = Bp + (size_t)(n0 + (w << 4) + srow) * KP + scol;
  unsigned short* const ldsw = lds + (w << 10);     // wave-uniform dest base

  // read offset: row = lane&15, col slot = (lane>>4) ^ (lane&7);
  // kc selects slot bit 2 via XOR (rdoff ^ (kc<<5))
  const int rdoff = ((lane & 15) << 6) + (((lane >> 4) ^ (lane & 7)) << 3);

#define STAGE2(tt, ht, cond)                                                   \
  if (cond) {                                                                  \
    const unsigned short* s_ =                                                 \
        ((ht) < 2 ? gA + (size_t)((ht) << 7) * KP                              \
                  : gB + (size_t)(((ht)-2) << 7) * KP) + (size_t)(tt)*BK;      \
    unsigned short* d_ = ldsw + ((((tt)&1) << 15) + ((ht) << 13));             \
    async_ld16(s_, d_);                                                        \
    async_ld16(s_ + (size_t)8 * KP, d_ + 512);                                 \
  }

#define LDA(bsel, mh, f, kc)                                                   \
  (*(const bf16x8*)&lds[((bsel) << 15) + (wr << 13) +                          \
                        (((mh)*64 + (f)*16) << 6) + (((kc) << 5) ^ rdoff)])
#define LDB(bsel, nh, g, kc)                                                   \
  (*(const bf16x8*)&lds[((bsel) << 15) + ((2 + (wc >> 1)) << 13) +             \
                        ((((wc & 1) * 64) + (nh)*32 + (g)*16) << 6) +          \
                        (((kc) << 5) ^ rdoff)])

#define MFMA(a, b, c) __builtin_amdgcn_mfma_f32_16x16x32_bf16((a), (b), (c), 0, 0, 0)

  // ---- prologue: stage tile0 + tile1 fully; wait tile0 (8 of 16 left) ----
  STAGE2(0, 0, true) STAGE2(0, 1, true) STAGE2(0, 2, true) STAGE2(0, 3, true)
  STAGE2(1, 0, true) STAGE2(1, 1, true) STAGE2(1, 2, true) STAGE2(1, 3, true)
  asm volatile("s_waitcnt vmcnt(8)" ::: "memory");   // tile0 fully landed
  __builtin_amdgcn_s_barrier();

  f32x4 acc[8][4] = {};
  bf16x8 a0[4][2], a1[4][2], bq[2][2];

#pragma unroll 2
  for (int t = 0; t < NT; ++t) {
    const int bsel = t & 1;
    // ---------- phase 0: quadrant (M0,N0); read a0 + b(N0) ----------
#pragma unroll
    for (int f = 0; f < 4; ++f) {
      a0[f][0] = LDA(bsel, 0, f, 0);
      a0[f][1] = LDA(bsel, 0, f, 1);
    }
#pragma unroll
    for (int g = 0; g < 2; ++g) {
      bq[g][0] = LDB(bsel, 0, g, 0);
      bq[g][1] = LDB(bsel, 0, g, 1);
    }
    __builtin_amdgcn_s_barrier();
    asm volatile("s_waitcnt lgkmcnt(0)" ::: "memory");
    __builtin_amdgcn_sched_barrier(0);
    __builtin_amdgcn_s_setprio(1);
#pragma unroll
    for (int f = 0; f < 4; ++f)
#pragma unroll
      for (int g = 0; g < 2; ++g) {
        acc[f][g] = MFMA(a0[f][0], bq[g][0], acc[f][g]);
        acc[f][g] = MFMA(a0[f][1], bq[g][1], acc[f][g]);
      }
    __builtin_amdgcn_s_setprio(0);
    __builtin_amdgcn_s_barrier();
    // ---------- phase 1: quadrant (M1,N0); read a1 ----------
#pragma unroll
    for (int f = 0; f < 4; ++f) {
      a1[f][0] = LDA(bsel, 1, f, 0);
      a1[f][1] = LDA(bsel, 1, f, 1);
    }
    __builtin_amdgcn_s_barrier();
    asm volatile("s_waitcnt lgkmcnt(0)" ::: "memory");
    __builtin_amdgcn_sched_barrier(0);
    __builtin_amdgcn_s_setprio(1);
#pragma unroll
    for (int f = 0; f < 4; ++f)
#pragma unroll
      for (int g = 0; g < 2; ++g) {
        acc[4 + f][g] = MFMA(a1[f][0], bq[g][0], acc[4 + f][g]);
        acc[4 + f][g] = MFMA(a1[f][1], bq[g][1], acc[4 + f][g]);
      }
    __builtin_amdgcn_s_setprio(0);
    __builtin_amdgcn_s_barrier();
    // ---------- phase 2: quadrant (M1,N1); read b(N1); stage A0+A1(t+2) ----
    // (all A reads of this buffer completed at phase-1 barrier)
#pragma unroll
    for (int g = 0; g < 2; ++g) {
      bq[g][0] = LDB(bsel, 1, g, 0);
      bq[g][1] = LDB(bsel, 1, g, 1);
    }
    STAGE2(t + 2, 0, t + 2 < NT)
    STAGE2(t + 2, 1, t + 2 < NT)
    __builtin_amdgcn_s_barrier();
    asm volatile("s_waitcnt lgkmcnt(0)" ::: "memory");
    __builtin_amdgcn_sched_barrier(0);
    __builtin_amdgcn_s_setprio(1);
#pragma unroll
    for (int f = 0; f < 4; ++f)
#pragma unroll
      for (int g = 0; g < 2; ++g) {
        acc[4 + f][2 + g] = MFMA(a1[f][0], bq[g][0], acc[4 + f][2 + g]);
        acc[4 + f][2 + g] = MFMA(a1[f][1], bq[g][1], acc[4 + f][2 + g]);
      }
    __builtin_amdgcn_s_setprio(0);
    __builtin_amdgcn_s_barrier();
    // ---------- phase 3: quadrant (M0,N1); reuse a0,bq; stage B2+B3(t+2) ---
    // (all B reads of this buffer completed at phase-2 barrier)
    STAGE2(t + 2, 2, t + 2 < NT)
    STAGE2(t + 2, 3, t + 2 < NT)
    __builtin_amdgcn_s_barrier();
    asm volatile("s_waitcnt lgkmcnt(0)" ::: "memory");
    __builtin_amdgcn_sched_barrier(0);
    __builtin_amdgcn_s_setprio(1);
#pragma unroll
    for (int f = 0; f < 4; ++f)
#pragma unroll
      for (int g = 0; g < 2; ++g) {
        acc[f][2 + g] = MFMA(a0[f][0], bq[g][0], acc[f][2 + g]);
        acc[f][2 + g] = MFMA(a0[f][1], bq[g][1], acc[f][2 + g]);
      }
    __builtin_amdgcn_s_setprio(0);
    // counted drain: ensure tile t+1 fully landed; keep tile t+2 (8 loads)
    // in flight. Full drain only when the pipeline is ending.
    if (t < NT - 2) {
      asm volatile("s_waitcnt vmcnt(8)" ::: "memory");
    } else if (t == NT - 2) {
      asm volatile("s_waitcnt vmcnt(0)" ::: "memory");
    }
    __builtin_amdgcn_s_barrier();
    __builtin_amdgcn_sched_barrier(0);
  }

  // ---- epilogue: bias + f32 store (C/D: col = lane&15, row = (lane>>4)*4+e) ----
  const int colL = lane & 15;
  const int rowG = lane >> 4;
#pragma unroll
  for (int nj = 0; nj < 4; ++nj) {
    const int n = n0 + wc * 64 + nj * 16 + colL;
    const float bv = bias[n];
#pragma unroll
    for (int mi = 0; mi < 8; ++mi) {
      const int mb = m0 + wr * 128 + mi * 16 + rowG * 4;
#pragma unroll
      for (int e = 0; e < 4; ++e)
        out[(size_t)(mb + e) * OUT_F + n] = acc[mi][nj][e] + bv;
    }
  }
#undef STAGE2
#undef LDA
#undef LDB
#undef MFMA
}

extern "C" void kernel_launch(void* const* d_in, const int* in_sizes, int n_in,
                              void* d_out, int out_size, void* d_ws, size_t ws_size,
                              hipStream_t stream) {
  (void)in_sizes; (void)n_in; (void)out_size; (void)ws_size;
  const float* x     = (const float*)d_in[0];
  const float* amax  = (const float*)d_in[1];
  const float* bias  = (const float*)d_in[2];
  const float* ldw   = (const float*)d_in[3];
  const float* luw   = (const float*)d_in[4];
  const float* alpha = (const float*)d_in[5];
  const int*   q     = (const int*)d_in[6];
  float* out = (float*)d_out;

  unsigned short* Ap = (unsigned short*)d_ws;                 // [NTOK][KP] bf16
  unsigned short* Bp = Ap + (size_t)NTOK * KP;                // [OUT_F][KP] bf16

  k_prep_a<<<NTOK / 4, 256, 0, stream>>>(x, ldw, Ap);
  k_prep_b<<<OUT_F, 256, 0, stream>>>(q, amax, luw, alpha, Bp);
  k_gemm<<<dim3(OUT_F / BN, NTOK / BM), 512, 0, stream>>>(Ap, Bp, bias, out);
}